// Round 3
// baseline (694.748 us; speedup 1.0000x reference)
//
#include <hip/hip_runtime.h>
#include <stdint.h>

#define Lc 96
#define Hc 8
#define Ec 64
#define EHc 128
#define APu 72           // A plane pitch in ushorts (144 B rows, 16B-aligned)
#define HPu 136          // H plane pitch in ushorts (272 B rows, 16B-aligned)
#define JS (Hc * Ec * 2) // out stride per j = 1024 floats

typedef __attribute__((ext_vector_type(8))) short short8;
typedef __attribute__((ext_vector_type(4))) float floatx4;

union FragH { uint16_t h[8]; short8 v; };

// tanh(x) = 1 - 2/(e^{2x}+1)
__device__ __forceinline__ float fast_tanh(float x) {
    const float e = __builtin_amdgcn_exp2f(x * 2.8853900817779268f);
    return 1.0f - 2.0f * __builtin_amdgcn_rcpf(e + 1.0f);
}

// barrier that drains LDS only — global stores stay in flight
__device__ __forceinline__ void lds_barrier() {
    asm volatile("s_waitcnt lgkmcnt(0)\n\ts_barrier" ::: "memory");
}

#define MF(acc, A, B) acc = __builtin_amdgcn_mfma_f32_16x16x32_bf16((A), (B), (acc), 0, 0, 0)

struct Pair { floatx4 o0, o1; };

// Block = 2 waves x 64 = 128 threads; M = 16 rows (one trajectory slice).
// Wave w owns: L1 hidden cols [64w,64w+64) (4 col-tiles), L2 out cols [32w,32w+32)
// (2 n-tiles => each lane carries 2 RK4 state columns). Halving the wave count
// halves total LDS read traffic (each wave reads full A and full H per eval).
// Same planar bf16 hi/lo LDS planes + ds_read_b128 frag reads as the verified
// round-1 kernel — only the work split changed; numerics are bitwise identical.
__global__ __launch_bounds__(128, 1)
void ode_mfma_kernel(const float* __restrict__ x, const float* __restrict__ ts,
                     const float* __restrict__ W1, const float* __restrict__ b1,
                     const float* __restrict__ W2, const float* __restrict__ b2,
                     float* __restrict__ out)
{
    __shared__ alignas(16) uint16_t A_hi[16 * APu];   // arg hi-bf16, [row][e]
    __shared__ alignas(16) uint16_t A_lo[16 * APu];   // arg lo-bf16
    __shared__ alignas(16) uint16_t H_hi[16 * HPu];   // hidden hi-bf16, [row][n]
    __shared__ alignas(16) uint16_t H_lo[16 * HPu];   // hidden lo-bf16
    __shared__ float tss[Lc];

    const int tid  = threadIdx.x;
    const int w    = tid >> 6;      // wave 0..1
    const int lane = tid & 63;
    const int g    = lane >> 4;     // quad 0..3
    const int c    = lane & 15;

    if (tid < Lc) tss[tid] = ts[tid];

    // ---- register-resident weight B-fragments: B[k = ks*32 + g*8 + j][n] ----
    short8 w1h[4][2], w1l[4][2];           // [ct][ks], n = 64w + 16ct + c
#pragma unroll
    for (int ct = 0; ct < 4; ++ct)
#pragma unroll
        for (int ks = 0; ks < 2; ++ks) {
            FragH fh, fl;
#pragma unroll
            for (int j = 0; j < 8; ++j) {
                const int k = ks * 32 + g * 8 + j;
                const int n = 64 * w + 16 * ct + c;
                const float v = W1[k * EHc + n];
                const uint32_t uv = __float_as_uint(v);
                const float hf = __uint_as_float(uv & 0xffff0000u);
                fh.h[j] = (uint16_t)(uv >> 16);
                fl.h[j] = (uint16_t)(__float_as_uint(v - hf) >> 16);
            }
            w1h[ct][ks] = fh.v; w1l[ct][ks] = fl.v;
        }
    short8 w2h[2][4], w2l[2][4];           // [nt][ks], n = 32w + 16nt + c
#pragma unroll
    for (int nt = 0; nt < 2; ++nt)
#pragma unroll
        for (int ks = 0; ks < 4; ++ks) {
            FragH fh, fl;
#pragma unroll
            for (int j = 0; j < 8; ++j) {
                const int k = ks * 32 + g * 8 + j;
                const int n = 32 * w + 16 * nt + c;
                const float v = W2[k * Ec + n];
                const uint32_t uv = __float_as_uint(v);
                const float hf = __uint_as_float(uv & 0xffff0000u);
                fh.h[j] = (uint16_t)(uv >> 16);
                fl.h[j] = (uint16_t)(__float_as_uint(v - hf) >> 16);
            }
            w2h[nt][ks] = fh.v; w2l[nt][ks] = fl.v;
        }

    float b1v[4], b2v[2];
#pragma unroll
    for (int ct = 0; ct < 4; ++ct) b1v[ct] = b1[64 * w + 16 * ct + c];
#pragma unroll
    for (int nt = 0; nt < 2; ++nt) b2v[nt] = b2[32 * w + 16 * nt + c];

    // ---- per-lane state: C/D layout, rows r = g*4+reg, cols 32w+16nt+c ----
    const int t_blk = (blockIdx.x * 16) >> 6;    // uniform: 16 divides 64
    const int fs    = (Lc - 1) - t_blk;          // forward step count
    const int col0  = 32 * w + c;

    float y0_[2][4], y_[2][4];
    float* outR[4];
#pragma unroll
    for (int reg = 0; reg < 4; ++reg) {
        const int rs = blockIdx.x * 16 + g * 4 + reg;   // global row-slot
        const int bidx = (rs & 63) >> 3;
        const int hh   = rs & 7;
        outR[reg] = out + (size_t)(bidx * Lc + t_blk) * (Lc * JS) + hh * (Ec * 2) + col0 * 2;
        const int r = g * 4 + reg;
#pragma unroll
        for (int nt = 0; nt < 2; ++nt) {
            const float v0 = x[((bidx * Lc + t_blk) * Hc + hh) * Ec + col0 + 16 * nt];
            y0_[nt][reg] = v0; y_[nt][reg] = v0;
            float2 o; o.x = v0; o.y = v0;               // j = t: (y0, y0)
            *(float2*)(outR[reg] + (size_t)t_blk * JS + nt * 32) = o;
            const uint32_t uv = __float_as_uint(v0);
            A_hi[r * APu + col0 + 16 * nt] = (uint16_t)(uv >> 16);
            A_lo[r * APu + col0 + 16 * nt] =
                (uint16_t)(__float_as_uint(v0 - __uint_as_float(uv & 0xffff0000u)) >> 16);
        }
    }
    __syncthreads();

    const int arow = c * APu + g * 8;    // A-frag base (u16 units), 16B-aligned
    const int hrow = c * HPu + g * 8;    // H-frag base

    // f(A planes) -> this lane's 2x4 output values (C/D layout). Entry: A synced.
    // One internal barrier (H handoff). Caller barriers after next A write.
    auto evalf = [&]() -> Pair {
        short8 ah[2], al[2];
        ah[0] = *(const short8*)(A_hi + arow);
        ah[1] = *(const short8*)(A_hi + arow + 32);
        al[0] = *(const short8*)(A_lo + arow);
        al[1] = *(const short8*)(A_lo + arow + 32);

        floatx4 p[4];
#pragma unroll
        for (int ct = 0; ct < 4; ++ct) {
            floatx4 acc = {b1v[ct], b1v[ct], b1v[ct], b1v[ct]};
            MF(acc, ah[0], w1h[ct][0]); MF(acc, ah[0], w1l[ct][0]); MF(acc, al[0], w1h[ct][0]);
            MF(acc, ah[1], w1h[ct][1]); MF(acc, ah[1], w1l[ct][1]); MF(acc, al[1], w1h[ct][1]);
            p[ct] = acc;
        }

#pragma unroll
        for (int ct = 0; ct < 4; ++ct) {
#pragma unroll
            for (int reg = 0; reg < 4; ++reg) {
                const int r = g * 4 + reg;
                const float t0 = fast_tanh(p[ct][reg]);
                const uint32_t u0 = __float_as_uint(t0);
                H_hi[r * HPu + 64 * w + 16 * ct + c] = (uint16_t)(u0 >> 16);
                H_lo[r * HPu + 64 * w + 16 * ct + c] =
                    (uint16_t)(__float_as_uint(t0 - __uint_as_float(u0 & 0xffff0000u)) >> 16);
            }
        }
        lds_barrier();

        const floatx4 z = {0.f, 0.f, 0.f, 0.f};
        floatx4 o0a = {b2v[0], b2v[0], b2v[0], b2v[0]}, o0b = z;
        floatx4 o1a = {b2v[1], b2v[1], b2v[1], b2v[1]}, o1b = z;
#pragma unroll
        for (int ks = 0; ks < 4; ++ks) {
            const short8 hh_ = *(const short8*)(H_hi + hrow + ks * 32);
            const short8 hl_ = *(const short8*)(H_lo + hrow + ks * 32);
            if (ks & 1) {
                MF(o0b, hh_, w2h[0][ks]); MF(o0b, hh_, w2l[0][ks]); MF(o0b, hl_, w2h[0][ks]);
                MF(o1b, hh_, w2h[1][ks]); MF(o1b, hh_, w2l[1][ks]); MF(o1b, hl_, w2h[1][ks]);
            } else {
                MF(o0a, hh_, w2h[0][ks]); MF(o0a, hh_, w2l[0][ks]); MF(o0a, hl_, w2h[0][ks]);
                MF(o1a, hh_, w2h[1][ks]); MF(o1a, hh_, w2l[1][ks]); MF(o1a, hl_, w2h[1][ks]);
            }
        }
        Pair r; r.o0 = o0a + o0b; r.o1 = o1a + o1b;
        return r;
    };

    auto putA = [&](const float (&a)[2][4]) {
#pragma unroll
        for (int nt = 0; nt < 2; ++nt)
#pragma unroll
            for (int reg = 0; reg < 4; ++reg) {
                const int r = g * 4 + reg;
                const float v = a[nt][reg];
                const uint32_t uv = __float_as_uint(v);
                A_hi[r * APu + col0 + 16 * nt] = (uint16_t)(uv >> 16);
                A_lo[r * APu + col0 + 16 * nt] =
                    (uint16_t)(__float_as_uint(v - __uint_as_float(uv & 0xffff0000u)) >> 16);
            }
        lds_barrier();
    };

    for (int v = 0; v < Lc - 1; ++v) {
        float dt; int jo;
        if (v < fs) { const int s = t_blk + v;        dt = tss[s + 1] - tss[s]; jo = s + 1; }
        else        { const int s = t_blk - (v - fs); dt = tss[s - 1] - tss[s]; jo = s - 1; }

        float a[2][4], k1[2][4], k2[2][4], k3[2][4];

        const Pair r1 = evalf();
#pragma unroll
        for (int reg = 0; reg < 4; ++reg) {
            k1[0][reg] = r1.o0[reg]; k1[1][reg] = r1.o1[reg];
#pragma unroll
            for (int nt = 0; nt < 2; ++nt)
                a[nt][reg] = fmaf(dt * (1.0f / 3.0f), k1[nt][reg], y_[nt][reg]);
        }
        putA(a);

        const Pair r2 = evalf();
#pragma unroll
        for (int reg = 0; reg < 4; ++reg) {
            k2[0][reg] = r2.o0[reg]; k2[1][reg] = r2.o1[reg];
#pragma unroll
            for (int nt = 0; nt < 2; ++nt)
                a[nt][reg] = y_[nt][reg] + dt * (k2[nt][reg] - (1.0f / 3.0f) * k1[nt][reg]);
        }
        putA(a);

        const Pair r3 = evalf();
#pragma unroll
        for (int reg = 0; reg < 4; ++reg) {
            k3[0][reg] = r3.o0[reg]; k3[1][reg] = r3.o1[reg];
#pragma unroll
            for (int nt = 0; nt < 2; ++nt)
                a[nt][reg] = y_[nt][reg] + dt * (k1[nt][reg] - k2[nt][reg] + k3[nt][reg]);
        }
        putA(a);

        const Pair r4 = evalf();
#pragma unroll
        for (int reg = 0; reg < 4; ++reg) {
            const float k4_0 = r4.o0[reg], k4_1 = r4.o1[reg];
            y_[0][reg] += dt * (k1[0][reg] + 3.0f * (k2[0][reg] + k3[0][reg]) + k4_0) * 0.125f;
            y_[1][reg] += dt * (k1[1][reg] + 3.0f * (k2[1][reg] + k3[1][reg]) + k4_1) * 0.125f;
#pragma unroll
            for (int nt = 0; nt < 2; ++nt) {
                float2 o; o.x = y0_[nt][reg]; o.y = y_[nt][reg];
                *(float2*)(outR[reg] + (size_t)jo * JS + nt * 32) = o;
            }
        }
        if (v + 1 == fs) {
#pragma unroll
            for (int nt = 0; nt < 2; ++nt)
#pragma unroll
                for (int reg = 0; reg < 4; ++reg) y_[nt][reg] = y0_[nt][reg];  // start bwd
        }
#pragma unroll
        for (int nt = 0; nt < 2; ++nt)
#pragma unroll
            for (int reg = 0; reg < 4; ++reg) a[nt][reg] = y_[nt][reg];
        putA(a);
    }
}

extern "C" void kernel_launch(void* const* d_in, const int* in_sizes, int n_in,
                              void* d_out, int out_size, void* d_ws, size_t ws_size,
                              hipStream_t stream) {
    const float* x  = (const float*)d_in[0];
    const float* ts = (const float*)d_in[1];
    const float* W1 = (const float*)d_in[2];
    const float* b1 = (const float*)d_in[3];
    const float* W2 = (const float*)d_in[4];
    const float* b2 = (const float*)d_in[5];
    float* out = (float*)d_out;

    dim3 grid(6144 / 16);   // 384 blocks x 16 rows = 96 traj x 64 rows
    dim3 block(128);        // 2 waves: halves total LDS read traffic vs 4-wave
    ode_mfma_kernel<<<grid, block, 0, stream>>>(x, ts, W1, b1, W2, b2, out);
}

// Round 4
// 649.710 us; speedup vs baseline: 1.0693x; 1.0693x over previous
//
#include <hip/hip_runtime.h>
#include <stdint.h>

#define Lc 96
#define Hc 8
#define Ec 64
#define EHc 128
#define APu 72           // A plane pitch in ushorts (144 B rows, 16B-aligned)
#define HPu 136          // H plane pitch in ushorts (272 B rows, 16B-aligned)
#define JS (Hc * Ec * 2) // out stride per j = 1024 floats

typedef __attribute__((ext_vector_type(8))) short short8;
typedef __attribute__((ext_vector_type(4))) float floatx4;

union FragH { uint16_t h[8]; short8 v; };

// tanh(x) = 1 - 2/(e^{2x}+1)
__device__ __forceinline__ float fast_tanh(float x) {
    const float e = __builtin_amdgcn_exp2f(x * 2.8853900817779268f);
    return 1.0f - 2.0f * __builtin_amdgcn_rcpf(e + 1.0f);
}

// barrier that drains LDS only — global stores stay in flight
__device__ __forceinline__ void lds_barrier() {
    asm volatile("s_waitcnt lgkmcnt(0)\n\ts_barrier" ::: "memory");
}

#define MF(acc, A, B) acc = __builtin_amdgcn_mfma_f32_16x16x32_bf16((A), (B), (acc), 0, 0, 0)

// Block = 4 waves x 64 = 256 threads; M = 16 rows (one trajectory slice).
// SWEEP-SPLIT: each 16-row tile is handled by TWO independent blocks —
// dir=0 integrates forward (t_blk -> 95), dir=1 backward (t_blk -> 0). Both
// start from S0, so they are fully independent; 768 blocks ~ 3/CU gives the
// latency-bound eval chain 2x more independent streams to hide under.
// Wave w owns: L1 hidden cols [32w,32w+32) (2 col-tiles), L2 out cols [16w,16w+16).
// Weights register-resident (bf16 hi/lo); activations round-trip LDS as planar
// bf16 hi/lo planes (b16 writes, ds_read_b128 fragment reads) — verified R1 mechanics.
__global__ __launch_bounds__(256, 2)
void ode_mfma_kernel(const float* __restrict__ x, const float* __restrict__ ts,
                     const float* __restrict__ W1, const float* __restrict__ b1,
                     const float* __restrict__ W2, const float* __restrict__ b2,
                     float* __restrict__ out)
{
    __shared__ alignas(16) uint16_t A_hi[16 * APu];   // arg hi-bf16, [row][e]
    __shared__ alignas(16) uint16_t A_lo[16 * APu];   // arg lo-bf16
    __shared__ alignas(16) uint16_t H_hi[16 * HPu];   // hidden hi-bf16, [row][n]
    __shared__ alignas(16) uint16_t H_lo[16 * HPu];   // hidden lo-bf16
    __shared__ float tss[Lc];

    const int tid  = threadIdx.x;
    const int w    = tid >> 6;      // wave 0..3
    const int lane = tid & 63;
    const int g    = lane >> 4;     // quad 0..3
    const int c    = lane & 15;

    const int tile  = blockIdx.x >> 1;           // 0..383
    const int dir   = blockIdx.x & 1;            // 0 = fwd, 1 = bwd
    const int t_blk = tile >> 2;                 // uniform: 16 divides 64
    const int nv    = dir ? t_blk : (Lc - 1 - t_blk);   // step count this block
    const int col   = 16 * w + c;

    // ---- per-lane state: C/D layout, rows r = g*4+reg, col e = 16w+c ----
    float y0_[4], y_[4];
    float* outp[4];
#pragma unroll
    for (int reg = 0; reg < 4; ++reg) {
        const int rs = tile * 16 + g * 4 + reg;         // global row-slot
        const int bidx = (rs & 63) >> 3;
        const int hh   = rs & 7;
        const float v0 = x[((bidx * Lc + t_blk) * Hc + hh) * Ec + col];
        y0_[reg] = v0; y_[reg] = v0;
        outp[reg] = out + (size_t)(bidx * Lc + t_blk) * (Lc * JS) + hh * (Ec * 2) + col * 2;
        if (dir == 0) {                                  // j = t: (y0, y0) — fwd block owns it
            float2 o; o.x = v0; o.y = v0;
            *(float2*)(outp[reg] + (size_t)t_blk * JS) = o;
        }
    }
    if (nv == 0) return;   // uniform per block: t_blk=95 fwd / t_blk=0 bwd

    if (tid < Lc) tss[tid] = ts[tid];

    // ---- register-resident weight B-fragments: B[k = ks*32 + g*8 + j][n] ----
    short8 w1h[2][2], w1l[2][2];           // [ct][ks]
#pragma unroll
    for (int ct = 0; ct < 2; ++ct)
#pragma unroll
        for (int ks = 0; ks < 2; ++ks) {
            FragH fh, fl;
#pragma unroll
            for (int j = 0; j < 8; ++j) {
                const int k = ks * 32 + g * 8 + j;
                const int n = 32 * w + 16 * ct + c;
                const float v = W1[k * EHc + n];
                const uint32_t uv = __float_as_uint(v);
                const float hf = __uint_as_float(uv & 0xffff0000u);
                fh.h[j] = (uint16_t)(uv >> 16);
                fl.h[j] = (uint16_t)(__float_as_uint(v - hf) >> 16);
            }
            w1h[ct][ks] = fh.v; w1l[ct][ks] = fl.v;
        }
    short8 w2h[4], w2l[4];                 // [ks]
#pragma unroll
    for (int ks = 0; ks < 4; ++ks) {
        FragH fh, fl;
#pragma unroll
        for (int j = 0; j < 8; ++j) {
            const int k = ks * 32 + g * 8 + j;
            const int n = 16 * w + c;
            const float v = W2[k * Ec + n];
            const uint32_t uv = __float_as_uint(v);
            const float hf = __uint_as_float(uv & 0xffff0000u);
            fh.h[j] = (uint16_t)(uv >> 16);
            fl.h[j] = (uint16_t)(__float_as_uint(v - hf) >> 16);
        }
        w2h[ks] = fh.v; w2l[ks] = fl.v;
    }

    const float b1v0 = b1[32 * w + c];
    const float b1v1 = b1[32 * w + 16 + c];
    const float b2v  = b2[16 * w + c];

    // initial argument into A planes
#pragma unroll
    for (int reg = 0; reg < 4; ++reg) {
        const int r = g * 4 + reg;
        const float v0 = y0_[reg];
        const uint32_t uv = __float_as_uint(v0);
        A_hi[r * APu + col] = (uint16_t)(uv >> 16);
        A_lo[r * APu + col] =
            (uint16_t)(__float_as_uint(v0 - __uint_as_float(uv & 0xffff0000u)) >> 16);
    }
    __syncthreads();

    const int arow = c * APu + g * 8;    // A-frag base (u16 units), 16B-aligned
    const int hrow = c * HPu + g * 8;    // H-frag base
    const int hcol = 32 * w + c;

    // f(A planes) -> this lane's 4 output values (C/D layout). Entry: A synced.
    // One internal barrier (H handoff). Caller barriers after next A write.
    auto evalf = [&]() -> floatx4 {
        const short8 a0h = *(const short8*)(A_hi + arow);
        const short8 a1h = *(const short8*)(A_hi + arow + 32);
        const short8 a0l = *(const short8*)(A_lo + arow);
        const short8 a1l = *(const short8*)(A_lo + arow + 32);

        const floatx4 z = {0.f, 0.f, 0.f, 0.f};
        floatx4 p0a = {b1v0, b1v0, b1v0, b1v0}, p0b = z;
        floatx4 p1a = {b1v1, b1v1, b1v1, b1v1}, p1b = z;
        __builtin_amdgcn_s_setprio(1);
        MF(p0a, a0h, w1h[0][0]); MF(p0a, a0h, w1l[0][0]); MF(p0a, a0l, w1h[0][0]);
        MF(p1a, a0h, w1h[1][0]); MF(p1a, a0h, w1l[1][0]); MF(p1a, a0l, w1h[1][0]);
        MF(p0b, a1h, w1h[0][1]); MF(p0b, a1h, w1l[0][1]); MF(p0b, a1l, w1h[0][1]);
        MF(p1b, a1h, w1h[1][1]); MF(p1b, a1h, w1l[1][1]); MF(p1b, a1l, w1h[1][1]);
        __builtin_amdgcn_s_setprio(0);
        const floatx4 p0 = p0a + p0b;
        const floatx4 p1 = p1a + p1b;

#pragma unroll
        for (int reg = 0; reg < 4; ++reg) {
            const int r = g * 4 + reg;
            const float t0 = fast_tanh(p0[reg]);
            const float t1 = fast_tanh(p1[reg]);
            const uint32_t u0 = __float_as_uint(t0);
            const uint32_t u1 = __float_as_uint(t1);
            H_hi[r * HPu + hcol]      = (uint16_t)(u0 >> 16);
            H_lo[r * HPu + hcol]      =
                (uint16_t)(__float_as_uint(t0 - __uint_as_float(u0 & 0xffff0000u)) >> 16);
            H_hi[r * HPu + hcol + 16] = (uint16_t)(u1 >> 16);
            H_lo[r * HPu + hcol + 16] =
                (uint16_t)(__float_as_uint(t1 - __uint_as_float(u1 & 0xffff0000u)) >> 16);
        }
        lds_barrier();

        floatx4 oa = {b2v, b2v, b2v, b2v}, ob = z, oc = z, od = z;
        const short8 h0 = *(const short8*)(H_hi + hrow);
        const short8 l0 = *(const short8*)(H_lo + hrow);
        const short8 h1 = *(const short8*)(H_hi + hrow + 32);
        const short8 l1 = *(const short8*)(H_lo + hrow + 32);
        const short8 h2 = *(const short8*)(H_hi + hrow + 64);
        const short8 l2 = *(const short8*)(H_lo + hrow + 64);
        const short8 h3 = *(const short8*)(H_hi + hrow + 96);
        const short8 l3 = *(const short8*)(H_lo + hrow + 96);
        __builtin_amdgcn_s_setprio(1);
        MF(oa, h0, w2h[0]); MF(oa, h0, w2l[0]); MF(oa, l0, w2h[0]);
        MF(ob, h1, w2h[1]); MF(ob, h1, w2l[1]); MF(ob, l1, w2h[1]);
        MF(oc, h2, w2h[2]); MF(oc, h2, w2l[2]); MF(oc, l2, w2h[2]);
        MF(od, h3, w2h[3]); MF(od, h3, w2l[3]); MF(od, l3, w2h[3]);
        __builtin_amdgcn_s_setprio(0);
        return (oa + ob) + (oc + od);
    };

    auto putA = [&](const float* a4) {
#pragma unroll
        for (int reg = 0; reg < 4; ++reg) {
            const int r = g * 4 + reg;
            const float v = a4[reg];
            const uint32_t uv = __float_as_uint(v);
            A_hi[r * APu + col] = (uint16_t)(uv >> 16);
            A_lo[r * APu + col] =
                (uint16_t)(__float_as_uint(v - __uint_as_float(uv & 0xffff0000u)) >> 16);
        }
        lds_barrier();
    };

    for (int v = 0; v < nv; ++v) {
        int s, jo;
        if (dir == 0) { s = t_blk + v; jo = s + 1; }
        else          { s = t_blk - v; jo = s - 1; }
        const float dt = tss[jo] - tss[s];

        float a[4];
        const floatx4 k1 = evalf();
#pragma unroll
        for (int reg = 0; reg < 4; ++reg)
            a[reg] = fmaf(dt * (1.0f / 3.0f), k1[reg], y_[reg]);
        putA(a);
        const floatx4 k2 = evalf();
#pragma unroll
        for (int reg = 0; reg < 4; ++reg)
            a[reg] = y_[reg] + dt * (k2[reg] - (1.0f / 3.0f) * k1[reg]);
        putA(a);
        const floatx4 k3 = evalf();
#pragma unroll
        for (int reg = 0; reg < 4; ++reg)
            a[reg] = y_[reg] + dt * (k1[reg] - k2[reg] + k3[reg]);
        putA(a);
        const floatx4 k4 = evalf();
#pragma unroll
        for (int reg = 0; reg < 4; ++reg) {
            y_[reg] += dt * (k1[reg] + 3.0f * (k2[reg] + k3[reg]) + k4[reg]) * 0.125f;
            float2 o; o.x = y0_[reg]; o.y = y_[reg];
            *(float2*)(outp[reg] + (size_t)jo * JS) = o;
        }
#pragma unroll
        for (int reg = 0; reg < 4; ++reg) a[reg] = y_[reg];
        putA(a);
    }
}

extern "C" void kernel_launch(void* const* d_in, const int* in_sizes, int n_in,
                              void* d_out, int out_size, void* d_ws, size_t ws_size,
                              hipStream_t stream) {
    const float* x  = (const float*)d_in[0];
    const float* ts = (const float*)d_in[1];
    const float* W1 = (const float*)d_in[2];
    const float* b1 = (const float*)d_in[3];
    const float* W2 = (const float*)d_in[4];
    const float* b2 = (const float*)d_in[5];
    float* out = (float*)d_out;

    dim3 grid(768);    // 384 tiles x {fwd, bwd} sweep-split blocks
    dim3 block(256);
    ode_mfma_kernel<<<grid, block, 0, stream>>>(x, ts, W1, b1, W2, b2, out);
}

// Round 5
// 564.126 us; speedup vs baseline: 1.2315x; 1.1517x over previous
//
#include <hip/hip_runtime.h>
#include <stdint.h>

#define Lc 96
#define Hc 8
#define Ec 64
#define EHc 128
#define APu 72           // A plane pitch in ushorts (144 B rows, 16B-aligned)
#define HPu 136          // H plane pitch in ushorts (272 B rows, 16B-aligned)
#define JS (Hc * Ec * 2) // out stride per j = 1024 floats

typedef __attribute__((ext_vector_type(8))) short short8;
typedef __attribute__((ext_vector_type(4))) float floatx4;

union FragH { uint16_t h[8]; short8 v; };

// tanh(x) = 1 - 2/(e^{2x}+1)
__device__ __forceinline__ float fast_tanh(float x) {
    const float e = __builtin_amdgcn_exp2f(x * 2.8853900817779268f);
    return 1.0f - 2.0f * __builtin_amdgcn_rcpf(e + 1.0f);
}

// barrier that drains LDS only — global stores stay in flight
__device__ __forceinline__ void lds_barrier() {
    asm volatile("s_waitcnt lgkmcnt(0)\n\ts_barrier" ::: "memory");
}

#define MF(acc, A, B) acc = __builtin_amdgcn_mfma_f32_16x16x32_bf16((A), (B), (acc), 0, 0, 0)

// Block = 8 waves x 64 = 512 threads; M = 16 rows (one trajectory slice).
// CHAIN-SHORTENING SPLIT: L1 (EH=128) is split 8 ways — wave w computes hidden
// cols [16w,16w+16) with only 6 MFMA + 4 tanh on the serial chain (vs 12+8 at
// 4 waves). Waves 0-3 additionally own the RK4 state / L2 out cols [16w,16w+16)
// (12 MFMA) and the A-plane writes; waves 4-7 idle between the two barriers.
// The 95-step serial chain is the makespan floor, so per-eval chain latency is
// the only lever. Sweep-split grid (fwd/bwd as separate blocks), longest first.
// No setprio (hurts lockstep blocks, m190 + R4 evidence).
__global__ __launch_bounds__(512, 2)
void ode_mfma_kernel(const float* __restrict__ x, const float* __restrict__ ts,
                     const float* __restrict__ W1, const float* __restrict__ b1,
                     const float* __restrict__ W2, const float* __restrict__ b2,
                     float* __restrict__ out)
{
    __shared__ alignas(16) uint16_t A_hi[16 * APu];   // arg hi-bf16, [row][e]
    __shared__ alignas(16) uint16_t A_lo[16 * APu];   // arg lo-bf16
    __shared__ alignas(16) uint16_t H_hi[16 * HPu];   // hidden hi-bf16, [row][n]
    __shared__ alignas(16) uint16_t H_lo[16 * HPu];   // hidden lo-bf16
    __shared__ float tss[Lc];

    const int tid  = threadIdx.x;
    const int w    = tid >> 6;      // wave 0..7
    const int lane = tid & 63;
    const int g    = lane >> 4;     // quad 0..3
    const int c    = lane & 15;

    // longest-first dispatch: fwd blocks take t ascending (len 95-t descending),
    // bwd blocks take t descending (len t descending).
    const int dir   = blockIdx.x & 1;            // 0 = fwd, 1 = bwd
    const int tile  = dir ? (383 - (blockIdx.x >> 1)) : (blockIdx.x >> 1);
    const int t_blk = tile >> 2;                 // uniform: 16 divides 64
    const int nv    = dir ? t_blk : (Lc - 1 - t_blk);   // step count this block
    const int col   = 16 * w + c;                // w<4: state/A/L2 column

    // ---- per-lane state (waves 0-3): C/D layout, rows r = g*4+reg ----
    float y0_[4], y_[4];
    float* outp0 = nullptr;
    if (w < 4) {
#pragma unroll
        for (int reg = 0; reg < 4; ++reg) {
            const int rs = tile * 16 + g * 4 + reg;     // global row-slot
            const int bidx = (rs & 63) >> 3;
            const int hh   = rs & 7;
            const float v0 = x[((bidx * Lc + t_blk) * Hc + hh) * Ec + col];
            y0_[reg] = v0; y_[reg] = v0;
            if (reg == 0)
                outp0 = out + (size_t)(bidx * Lc + t_blk) * (Lc * JS) + hh * (Ec * 2) + col * 2;
            if (dir == 0) {                              // j = t: (y0, y0) — fwd owns it
                float2 o; o.x = v0; o.y = v0;
                *(float2*)(outp0 + reg * (Ec * 2) + (size_t)t_blk * JS) = o;
            }
        }
    }
    if (nv == 0) return;   // uniform per block: t_blk=95 fwd / t_blk=0 bwd

    if (tid < Lc) tss[tid] = ts[tid];

    // ---- register-resident weight B-fragments: B[k = ks*32 + g*8 + j][n] ----
    // L1: wave w owns ONE hidden col-tile, n = 16w + c.
    short8 w1h[2], w1l[2];                 // [ks]
#pragma unroll
    for (int ks = 0; ks < 2; ++ks) {
        FragH fh, fl;
#pragma unroll
        for (int j = 0; j < 8; ++j) {
            const int k = ks * 32 + g * 8 + j;
            const float v = W1[k * EHc + col];
            const uint32_t uv = __float_as_uint(v);
            const float hf = __uint_as_float(uv & 0xffff0000u);
            fh.h[j] = (uint16_t)(uv >> 16);
            fl.h[j] = (uint16_t)(__float_as_uint(v - hf) >> 16);
        }
        w1h[ks] = fh.v; w1l[ks] = fl.v;
    }
    // L2 (waves 0-3): out col-tile n = 16w + c.
    short8 w2h[4], w2l[4];                 // [ks]
    if (w < 4) {
#pragma unroll
        for (int ks = 0; ks < 4; ++ks) {
            FragH fh, fl;
#pragma unroll
            for (int j = 0; j < 8; ++j) {
                const int k = ks * 32 + g * 8 + j;
                const float v = W2[k * Ec + col];
                const uint32_t uv = __float_as_uint(v);
                const float hf = __uint_as_float(uv & 0xffff0000u);
                fh.h[j] = (uint16_t)(uv >> 16);
                fl.h[j] = (uint16_t)(__float_as_uint(v - hf) >> 16);
            }
            w2h[ks] = fh.v; w2l[ks] = fl.v;
        }
    }

    const float b1v = b1[col & 127];         // wave's hidden col (w 0..7 -> n 0..127)
    const float b2v = (w < 4) ? b2[col] : 0.f;

    // initial argument into A planes (waves 0-3 hold the state)
    if (w < 4) {
#pragma unroll
        for (int reg = 0; reg < 4; ++reg) {
            const int r = g * 4 + reg;
            const float v0 = y0_[reg];
            const uint32_t uv = __float_as_uint(v0);
            A_hi[r * APu + col] = (uint16_t)(uv >> 16);
            A_lo[r * APu + col] =
                (uint16_t)(__float_as_uint(v0 - __uint_as_float(uv & 0xffff0000u)) >> 16);
        }
    }
    __syncthreads();

    const int arow = c * APu + g * 8;    // A-frag base (u16 units), 16B-aligned
    const int hrow = c * HPu + g * 8;    // H-frag base
    const int hcol = 16 * w + c;         // this wave's hidden col

    // f(A planes) -> lane's 4 output values (waves 0-3; others return zeros).
    // Entry: A synced. One internal barrier (H handoff). Caller barriers after
    // the next A write (putA). All waves execute both barriers.
    auto evalf = [&]() -> floatx4 {
        const short8 a0h = *(const short8*)(A_hi + arow);
        const short8 a1h = *(const short8*)(A_hi + arow + 32);
        const short8 a0l = *(const short8*)(A_lo + arow);
        const short8 a1l = *(const short8*)(A_lo + arow + 32);

        floatx4 p = {b1v, b1v, b1v, b1v};
        MF(p, a0h, w1h[0]); MF(p, a0h, w1l[0]); MF(p, a0l, w1h[0]);
        MF(p, a1h, w1h[1]); MF(p, a1h, w1l[1]); MF(p, a1l, w1h[1]);

#pragma unroll
        for (int reg = 0; reg < 4; ++reg) {
            const int r = g * 4 + reg;
            const float t0 = fast_tanh(p[reg]);
            const uint32_t u0 = __float_as_uint(t0);
            H_hi[r * HPu + hcol] = (uint16_t)(u0 >> 16);
            H_lo[r * HPu + hcol] =
                (uint16_t)(__float_as_uint(t0 - __uint_as_float(u0 & 0xffff0000u)) >> 16);
        }
        lds_barrier();

        const floatx4 z = {0.f, 0.f, 0.f, 0.f};
        floatx4 oa = z, ob = z, oc = z, od = z;
        if (w < 4) {
            oa.x = b2v; oa.y = b2v; oa.z = b2v; oa.w = b2v;
            const short8 h0 = *(const short8*)(H_hi + hrow);
            const short8 l0 = *(const short8*)(H_lo + hrow);
            const short8 h1 = *(const short8*)(H_hi + hrow + 32);
            const short8 l1 = *(const short8*)(H_lo + hrow + 32);
            const short8 h2 = *(const short8*)(H_hi + hrow + 64);
            const short8 l2 = *(const short8*)(H_lo + hrow + 64);
            const short8 h3 = *(const short8*)(H_hi + hrow + 96);
            const short8 l3 = *(const short8*)(H_lo + hrow + 96);
            MF(oa, h0, w2h[0]); MF(oa, h0, w2l[0]); MF(oa, l0, w2h[0]);
            MF(ob, h1, w2h[1]); MF(ob, h1, w2l[1]); MF(ob, l1, w2h[1]);
            MF(oc, h2, w2h[2]); MF(oc, h2, w2l[2]); MF(oc, l2, w2h[2]);
            MF(od, h3, w2h[3]); MF(od, h3, w2l[3]); MF(od, l3, w2h[3]);
        }
        return (oa + ob) + (oc + od);
    };

    auto putA = [&](const float* a4) {
        if (w < 4) {
#pragma unroll
            for (int reg = 0; reg < 4; ++reg) {
                const int r = g * 4 + reg;
                const float v = a4[reg];
                const uint32_t uv = __float_as_uint(v);
                A_hi[r * APu + col] = (uint16_t)(uv >> 16);
                A_lo[r * APu + col] =
                    (uint16_t)(__float_as_uint(v - __uint_as_float(uv & 0xffff0000u)) >> 16);
            }
        }
        lds_barrier();
    };

    for (int v = 0; v < nv; ++v) {
        int s, jo;
        if (dir == 0) { s = t_blk + v; jo = s + 1; }
        else          { s = t_blk - v; jo = s - 1; }
        const float dt = tss[jo] - tss[s];

        float a[4];
        const floatx4 k1 = evalf();
#pragma unroll
        for (int reg = 0; reg < 4; ++reg)
            a[reg] = fmaf(dt * (1.0f / 3.0f), k1[reg], y_[reg]);
        putA(a);
        const floatx4 k2 = evalf();
#pragma unroll
        for (int reg = 0; reg < 4; ++reg)
            a[reg] = y_[reg] + dt * (k2[reg] - (1.0f / 3.0f) * k1[reg]);
        putA(a);
        const floatx4 k3 = evalf();
#pragma unroll
        for (int reg = 0; reg < 4; ++reg)
            a[reg] = y_[reg] + dt * (k1[reg] - k2[reg] + k3[reg]);
        putA(a);
        const floatx4 k4 = evalf();
        if (w < 4) {
#pragma unroll
            for (int reg = 0; reg < 4; ++reg) {
                y_[reg] += dt * (k1[reg] + 3.0f * (k2[reg] + k3[reg]) + k4[reg]) * 0.125f;
                float2 o; o.x = y0_[reg]; o.y = y_[reg];
                *(float2*)(outp0 + reg * (Ec * 2) + (size_t)jo * JS) = o;
            }
        }
#pragma unroll
        for (int reg = 0; reg < 4; ++reg) a[reg] = y_[reg];
        putA(a);
    }
}

extern "C" void kernel_launch(void* const* d_in, const int* in_sizes, int n_in,
                              void* d_out, int out_size, void* d_ws, size_t ws_size,
                              hipStream_t stream) {
    const float* x  = (const float*)d_in[0];
    const float* ts = (const float*)d_in[1];
    const float* W1 = (const float*)d_in[2];
    const float* b1 = (const float*)d_in[3];
    const float* W2 = (const float*)d_in[4];
    const float* b2 = (const float*)d_in[5];
    float* out = (float*)d_out;

    dim3 grid(768);    // 384 tiles x {fwd, bwd}, longest sweeps dispatched first
    dim3 block(512);   // 8 waves: L1 split 8-way to shorten the serial eval chain
    ode_mfma_kernel<<<grid, block, 0, stream>>>(x, ts, W1, b1, W2, b2, out);
}

// Round 8
// 518.709 us; speedup vs baseline: 1.3394x; 1.0876x over previous
//
#include <hip/hip_runtime.h>
#include <stdint.h>

#define Lc 96
#define Hc 8
#define Ec 64
#define EHc 128
#define APu 72           // A plane pitch in ushorts (144 B rows, 16B-aligned)
#define HPu 136          // H plane pitch in ushorts (272 B rows, 16B-aligned)
#define JS (Hc * Ec * 2) // out stride per j = 1024 floats

typedef __attribute__((ext_vector_type(8))) short short8;
typedef __attribute__((ext_vector_type(4))) float floatx4;

union FragH { uint16_t h[8]; short8 v; };

// tanh(x) = 1 - 2/(e^{2x}+1)
__device__ __forceinline__ float fast_tanh(float x) {
    const float e = __builtin_amdgcn_exp2f(x * 2.8853900817779268f);
    return 1.0f - 2.0f * __builtin_amdgcn_rcpf(e + 1.0f);
}

// barrier that drains LDS only — global stores stay in flight.
// sched_barrier(0) fences stop the compiler moving ANY op across the asm
// (rule #18 class hazard insurance; zero runtime cost).
__device__ __forceinline__ void lds_barrier() {
    __builtin_amdgcn_sched_barrier(0);
    asm volatile("s_waitcnt lgkmcnt(0)\n\ts_barrier" ::: "memory");
    __builtin_amdgcn_sched_barrier(0);
}

#define MF(acc, A, B) acc = __builtin_amdgcn_mfma_f32_16x16x32_bf16((A), (B), (acc), 0, 0, 0)

// Block = 8 waves x 64 = 512 threads; M = 16 rows (one trajectory slice).
// SWEEP-SPLIT (verified R5 structure): each tile handled by TWO independent
// blocks — dir=0 fwd (t->95), dir=1 bwd (t->0); longest sweeps dispatched first.
// 8-WAVE CHAIN SPLIT: wave w computes L1 hidden cols [16w,16w+16) (6 MFMA on
// the chain); waves 0-3 additionally own RK4 state / L2 out cols [16w,16w+16).
// PRECISION BUDGET: H (post-tanh, |H|<=1) is stored hi-bf16 ONLY — the lo-H
// correction term in L2 is dropped (error ~1e-3/eval, ~0.03 total vs 0.33
// threshold). A keeps hi+lo. L2 = 8 MFMA, H traffic halved.
__global__ __launch_bounds__(512, 2)
void ode_mfma_kernel(const float* __restrict__ x, const float* __restrict__ ts,
                     const float* __restrict__ W1, const float* __restrict__ b1,
                     const float* __restrict__ W2, const float* __restrict__ b2,
                     float* __restrict__ out)
{
    __shared__ alignas(16) uint16_t A_hi[16 * APu];   // arg hi-bf16, [row][e]
    __shared__ alignas(16) uint16_t A_lo[16 * APu];   // arg lo-bf16
    __shared__ alignas(16) uint16_t H_hi[16 * HPu];   // hidden hi-bf16, [row][n]
    __shared__ float tss[Lc];

    const int tid  = threadIdx.x;
    const int w    = tid >> 6;      // wave 0..7
    const int lane = tid & 63;
    const int g    = lane >> 4;     // quad 0..3
    const int c    = lane & 15;

    // longest-first dispatch: fwd blocks take t ascending (len 95-t descending),
    // bwd blocks take t descending (len t descending).
    const int dir   = blockIdx.x & 1;            // 0 = fwd, 1 = bwd
    const int tile  = dir ? (383 - (blockIdx.x >> 1)) : (blockIdx.x >> 1);
    const int t_blk = tile >> 2;                 // uniform: 16 divides 64
    const int nv    = dir ? t_blk : (Lc - 1) - t_blk;   // step count this block
    const int col   = 16 * w + c;                // w<4: state/A/L2 column

    // ---- per-lane state (waves 0-3): C/D layout, rows r = g*4+reg ----
    float y0_[4], y_[4];
    float* outp0 = nullptr;
    if (w < 4) {
#pragma unroll
        for (int reg = 0; reg < 4; ++reg) {
            const int rs = tile * 16 + g * 4 + reg;     // global row-slot
            const int bidx = (rs & 63) >> 3;
            const int hh   = rs & 7;
            const float v0 = x[((bidx * Lc + t_blk) * Hc + hh) * Ec + col];
            y0_[reg] = v0; y_[reg] = v0;
            if (reg == 0)
                outp0 = out + (size_t)(bidx * Lc + t_blk) * (Lc * JS) + hh * (Ec * 2) + col * 2;
            if (dir == 0) {                              // j = t: (y0, y0) — fwd owns it
                float2 o; o.x = v0; o.y = v0;
                *(float2*)(outp0 + reg * (Ec * 2) + (size_t)t_blk * JS) = o;
            }
        }
    }
    if (nv == 0) return;   // uniform per block: t_blk=95 fwd / t_blk=0 bwd

    if (tid < Lc) tss[tid] = ts[tid];

    // ---- register-resident weight B-fragments: B[k = ks*32 + g*8 + j][n] ----
    // L1: wave w owns ONE hidden col-tile, n = 16w + c.
    short8 w1h[2], w1l[2];                 // [ks]
#pragma unroll
    for (int ks = 0; ks < 2; ++ks) {
        FragH fh, fl;
#pragma unroll
        for (int j = 0; j < 8; ++j) {
            const int k = ks * 32 + g * 8 + j;
            const float v = W1[k * EHc + col];
            const uint32_t uv = __float_as_uint(v);
            const float hf = __uint_as_float(uv & 0xffff0000u);
            fh.h[j] = (uint16_t)(uv >> 16);
            fl.h[j] = (uint16_t)(__float_as_uint(v - hf) >> 16);
        }
        w1h[ks] = fh.v; w1l[ks] = fl.v;
    }
    // L2 (waves 0-3): out col-tile n = 16w + c.
    short8 w2h[4], w2l[4];                 // [ks]
    if (w < 4) {
#pragma unroll
        for (int ks = 0; ks < 4; ++ks) {
            FragH fh, fl;
#pragma unroll
            for (int j = 0; j < 8; ++j) {
                const int k = ks * 32 + g * 8 + j;
                const float v = W2[k * Ec + col];
                const uint32_t uv = __float_as_uint(v);
                const float hf = __uint_as_float(uv & 0xffff0000u);
                fh.h[j] = (uint16_t)(uv >> 16);
                fl.h[j] = (uint16_t)(__float_as_uint(v - hf) >> 16);
            }
            w2h[ks] = fh.v; w2l[ks] = fl.v;
        }
    }

    const float b1v = b1[col & 127];         // wave's hidden col (w 0..7 -> n 0..127)
    const float b2v = (w < 4) ? b2[col] : 0.f;

    // initial argument into A planes (waves 0-3 hold the state)
    if (w < 4) {
#pragma unroll
        for (int reg = 0; reg < 4; ++reg) {
            const int r = g * 4 + reg;
            const float v0 = y0_[reg];
            const uint32_t uv = __float_as_uint(v0);
            A_hi[r * APu + col] = (uint16_t)(uv >> 16);
            A_lo[r * APu + col] =
                (uint16_t)(__float_as_uint(v0 - __uint_as_float(uv & 0xffff0000u)) >> 16);
        }
    }
    __syncthreads();

    const int arow = c * APu + g * 8;    // A-frag base (u16 units), 16B-aligned
    const int hrow = c * HPu + g * 8;    // H-frag base
    const int hcol = 16 * w + c;         // this wave's hidden col

    // f(A planes) -> lane's 4 output values (waves 0-3; others return zeros).
    // Entry: A synced. One internal barrier (H handoff). Caller barriers after
    // the next A write (putA). All waves execute both barriers.
    auto evalf = [&]() -> floatx4 {
        const short8 a0h = *(const short8*)(A_hi + arow);
        const short8 a1h = *(const short8*)(A_hi + arow + 32);
        const short8 a0l = *(const short8*)(A_lo + arow);
        const short8 a1l = *(const short8*)(A_lo + arow + 32);

        const floatx4 z = {0.f, 0.f, 0.f, 0.f};
        floatx4 pa = {b1v, b1v, b1v, b1v}, pb = z;   // 2 chains: halve dep depth
        MF(pa, a0h, w1h[0]); MF(pa, a0h, w1l[0]); MF(pa, a0l, w1h[0]);
        MF(pb, a1h, w1h[1]); MF(pb, a1h, w1l[1]); MF(pb, a1l, w1h[1]);
        const floatx4 p = pa + pb;

#pragma unroll
        for (int reg = 0; reg < 4; ++reg) {
            const int r = g * 4 + reg;
            const float t0 = fast_tanh(p[reg]);
            H_hi[r * HPu + hcol] = (uint16_t)(__float_as_uint(t0) >> 16);
        }
        lds_barrier();

        floatx4 oa = z, ob = z, oc = z, od = z;
        if (w < 4) {
            oa.x = b2v; oa.y = b2v; oa.z = b2v; oa.w = b2v;
            const short8 h0 = *(const short8*)(H_hi + hrow);
            const short8 h1 = *(const short8*)(H_hi + hrow + 32);
            const short8 h2 = *(const short8*)(H_hi + hrow + 64);
            const short8 h3 = *(const short8*)(H_hi + hrow + 96);
            MF(oa, h0, w2h[0]); MF(oa, h0, w2l[0]);
            MF(ob, h1, w2h[1]); MF(ob, h1, w2l[1]);
            MF(oc, h2, w2h[2]); MF(oc, h2, w2l[2]);
            MF(od, h3, w2h[3]); MF(od, h3, w2l[3]);
        }
        return (oa + ob) + (oc + od);
    };

    auto putA = [&](const float* a4) {
        if (w < 4) {
#pragma unroll
            for (int reg = 0; reg < 4; ++reg) {
                const int r = g * 4 + reg;
                const float v = a4[reg];
                const uint32_t uv = __float_as_uint(v);
                A_hi[r * APu + col] = (uint16_t)(uv >> 16);
                A_lo[r * APu + col] =
                    (uint16_t)(__float_as_uint(v - __uint_as_float(uv & 0xffff0000u)) >> 16);
            }
        }
        lds_barrier();
    };

    for (int v = 0; v < nv; ++v) {
        int s, jo;
        if (dir == 0) { s = t_blk + v; jo = s + 1; }
        else          { s = t_blk - v; jo = s - 1; }
        const float dt = tss[jo] - tss[s];

        float a[4];
        const floatx4 k1 = evalf();
#pragma unroll
        for (int reg = 0; reg < 4; ++reg)
            a[reg] = fmaf(dt * (1.0f / 3.0f), k1[reg], y_[reg]);
        putA(a);
        const floatx4 k2 = evalf();
#pragma unroll
        for (int reg = 0; reg < 4; ++reg)
            a[reg] = y_[reg] + dt * (k2[reg] - (1.0f / 3.0f) * k1[reg]);
        putA(a);
        const floatx4 k3 = evalf();
#pragma unroll
        for (int reg = 0; reg < 4; ++reg)
            a[reg] = y_[reg] + dt * (k1[reg] - k2[reg] + k3[reg]);
        putA(a);
        const floatx4 k4 = evalf();
        if (w < 4) {
#pragma unroll
            for (int reg = 0; reg < 4; ++reg)
                y_[reg] += dt * (k1[reg] + 3.0f * (k2[reg] + k3[reg]) + k4[reg]) * 0.125f;
        }
#pragma unroll
        for (int reg = 0; reg < 4; ++reg) a[reg] = y_[reg];
        putA(a);
        if (w < 4) {                     // out-store AFTER the barrier: off the
#pragma unroll                           // chain; fire-and-forget (no vmcnt drain)
            for (int reg = 0; reg < 4; ++reg) {
                float2 o; o.x = y0_[reg]; o.y = y_[reg];
                *(float2*)(outp0 + reg * (Ec * 2) + (size_t)jo * JS) = o;
            }
        }
    }
}

extern "C" void kernel_launch(void* const* d_in, const int* in_sizes, int n_in,
                              void* d_out, int out_size, void* d_ws, size_t ws_size,
                              hipStream_t stream) {
    const float* x  = (const float*)d_in[0];
    const float* ts = (const float*)d_in[1];
    const float* W1 = (const float*)d_in[2];
    const float* b1 = (const float*)d_in[3];
    const float* W2 = (const float*)d_in[4];
    const float* b2 = (const float*)d_in[5];
    float* out = (float*)d_out;

    dim3 grid(768);    // 384 tiles x {fwd, bwd}, longest sweeps dispatched first
    dim3 block(512);   // 8 waves: L1 split 8-way to shorten the serial eval chain
    ode_mfma_kernel<<<grid, block, 0, stream>>>(x, ts, W1, b1, W2, b2, out);
}